// Round 1
// baseline (76.042 us; speedup 1.0000x reference)
//
#include <hip/hip_runtime.h>

// BatchedLUTNodes: out[b,n] = 6-D multilinear interpolation of tables[n,0..63]
// at coords x[b,n,0..5] clipped to [0,1]. 63 lerps/output (verified R1).
//
// R3 change vs R2: drop LDS staging entirely. R2 was latency-bound, not
// throughput-bound: stage -> barrier -> 64x ds_read_b32 t-fill was a serial
// chain with only 4 waves/SIMD to hide it, and per-CU ds_read issue alone
// (16 waves x 64 x 5.8cy ~ 5.9k cyc) exceeded the VALU work. Tables (2 MB)
// are L2-resident per XCD: the 8 blocks sharing a node tile are blockIdx
// multiples of 128 apart (128 % 8 == 0 -> same XCD), so a direct
// global->reg dwordx4 t-fill is HBM-once, L2-served after.
//
// Also: level-0 (base,diff) precomputed once per thread and reused across
// the 4 batches (saves 32 subs x 3); sequential folds + 1-deep x prefetch
// keep VGPR <= 128 so __launch_bounds__(256,4) holds 4 waves/SIMD.

#define THREADS 256

__global__ __launch_bounds__(THREADS, 4)
void lut_fold_kernel(const float* __restrict__ x,
                     const float* __restrict__ tables,
                     float* __restrict__ out) {
    const int tid       = threadIdx.x;
    const int node_tile = blockIdx.x & 127;   // 128 node tiles; same tile => same XCD
    const int bgroup    = blockIdx.x >> 7;    // 8 batch groups
    const int n_local   = tid & 63;
    const int bq        = tid >> 6;           // 4 batch subgroups
    const int n         = node_tile * 64 + n_local;
    const int bbase     = bgroup * 16 + bq * 4;

    // ---- table row -> registers as level-0 (base, diff) pairs ----
    // 16x global_load_dwordx4, lane stride 256 B; wave working set 16 KB
    // (L1-resident), tile shared by 8 same-XCD blocks via L2.
    float tb[32], td[32];
    {
        const float4* tp = (const float4*)(tables + n * 64);
        #pragma unroll
        for (int k = 0; k < 16; ++k) {
            const float4 v = tp[k];           // entries 4k .. 4k+3
            tb[2 * k]     = v.x;  td[2 * k]     = v.y - v.x;
            tb[2 * k + 1] = v.z;  td[2 * k + 1] = v.w - v.z;
        }
    }

    // ---- 1-deep prefetched x (24 B/thread/batch, float2 x3, 8B-aligned) ----
    float2 q0, q1, q2;
    {
        const float2* xp = (const float2*)(x + (bbase * 8192 + n) * 6);
        q0 = xp[0]; q1 = xp[1]; q2 = xp[2];
    }

    #pragma unroll
    for (int bl = 0; bl < 4; ++bl) {
        const float x0 = fminf(fmaxf(q0.x, 0.f), 1.f);
        const float x1 = fminf(fmaxf(q0.y, 0.f), 1.f);
        const float x2 = fminf(fmaxf(q1.x, 0.f), 1.f);
        const float x3 = fminf(fmaxf(q1.y, 0.f), 1.f);
        const float x4 = fminf(fmaxf(q2.x, 0.f), 1.f);
        const float x5 = fminf(fmaxf(q2.y, 0.f), 1.f);

        if (bl < 3) {  // prefetch next batch's coords under this fold
            const float2* xn = (const float2*)(x + ((bbase + bl + 1) * 8192 + n) * 6);
            q0 = xn[0]; q1 = xn[1]; q2 = xn[2];
        }

        float a[32];
        #pragma unroll
        for (int j = 0; j < 32; ++j) a[j] = fmaf(x0, td[j], tb[j]);
        #pragma unroll
        for (int j = 0; j < 16; ++j) a[j] = fmaf(x1, a[2*j+1] - a[2*j], a[2*j]);
        #pragma unroll
        for (int j = 0; j < 8;  ++j) a[j] = fmaf(x2, a[2*j+1] - a[2*j], a[2*j]);
        #pragma unroll
        for (int j = 0; j < 4;  ++j) a[j] = fmaf(x3, a[2*j+1] - a[2*j], a[2*j]);
        #pragma unroll
        for (int j = 0; j < 2;  ++j) a[j] = fmaf(x4, a[2*j+1] - a[2*j], a[2*j]);
        const float r = fmaf(x5, a[1] - a[0], a[0]);

        out[(bbase + bl) * 8192 + n] = r;     // coalesced b32
    }
}

extern "C" void kernel_launch(void* const* d_in, const int* in_sizes, int n_in,
                              void* d_out, int out_size, void* d_ws, size_t ws_size,
                              hipStream_t stream) {
    const float* x      = (const float*)d_in[0];   // 128*8192*6 f32
    const float* tables = (const float*)d_in[1];   // 8192*64 f32
    float* out          = (float*)d_out;           // 128*8192 f32

    dim3 grid(1024);   // 128 node tiles x 8 batch groups = 4 blocks/CU
    dim3 block(THREADS);
    hipLaunchKernelGGL(lut_fold_kernel, grid, block, 0, stream, x, tables, out);
}

// Round 2
// 71.504 us; speedup vs baseline: 1.0635x; 1.0635x over previous
//
#include <hip/hip_runtime.h>

// BatchedLUTNodes: out[b,n] = 6-D multilinear interpolation of tables[n,0..63]
// at coords x[b,n,0..5] clipped to [0,1]. 63 lerps/output (verified R1,
// absmax 3.9e-3 << 1.8e-2).
//
// R4 = R2 structure (LDS staging — R3 proved direct global t-fill is WORSE:
// lane-stride-256B dwordx4 touches 64 cache lines/instr, 4x the L1
// transactions; total 76.0 vs 71.9) with three kernel-side fixes:
//
// 1. t-fill: 64x ds_read_b32 (371 cy/wave issue) -> 16x ds_read_b128
//    (192 cy/wave) via XOR-16 block swizzle. Layout: row r's logical
//    float4-block k lives at physical block (k ^ (r & 15)), unpadded
//    [64][64]. Per 16-lane phase, rows 0..15 reading logical k hit
//    physical blocks {k^0..k^15} = all 16 -> 64 distinct floats ->
//    2 lanes/bank = free (m136). R2's "don't use b128" note analyzed
//    UNSWIZZLED stride-64/68 layouts; the swizzle removes the conflict.
//    Staging writes are likewise a per-row block permutation -> free.
// 2. Level-0 (base,diff) precomputed once per thread, reused across the
//    4 batches (saves 96 v_sub/thread vs R2's per-batch t[2j+1]-t[2j]).
// 3. Depth-2 rolling x-prefetch (p[2][3], fully unrolled -> static idx)
//    instead of the 4-batch hoist: VGPR ~122 <= 128 so
//    __launch_bounds__(256,4) holds 4 waves/SIMD (R2 was ~130-160 -> 3).
//
// Decision rule: if total >= 71 us (no better than R2), the ws-poison fill
// (44 us, HBM-roofline) + restore dispatch overhead dominate and the
// kernel is at its floor -> declare ROOFLINE.

#define THREADS 256
#define NPB 64   // nodes per block

__global__ __launch_bounds__(THREADS, 4)
void lut_fold_kernel(const float* __restrict__ x,
                     const float* __restrict__ tables,
                     float* __restrict__ out) {
    __shared__ float lt[NPB * 64];   // XOR-swizzled, unpadded (16 KB)

    const int tid       = threadIdx.x;
    const int node_tile = blockIdx.x & 127;   // 128 node tiles
    const int bgroup    = blockIdx.x >> 7;    // 8 batch groups
    const int node0     = node_tile * NPB;
    const int b0        = bgroup * 16;

    // ---- Stage 64x64 table tile into LDS (swizzled), 4x dwordx4/thread ----
    {
        const float4* gt4 = (const float4*)(tables + (long)node0 * 64);
        #pragma unroll
        for (int k = 0; k < (NPB * 64) / (THREADS * 4); ++k) {
            const int g4  = tid + THREADS * k;   // logical float4 idx 0..1023
            const float4 v = gt4[g4];            // coalesced 16 B/lane
            const int row = g4 >> 4;             // 16 blocks per row
            const int cb  = g4 & 15;             // logical block in row
            *(float4*)&lt[row * 64 + ((cb ^ (row & 15)) << 2)] = v;
        }
    }
    __syncthreads();

    const int n_local = tid & 63;   // node within tile == LDS row
    const int bq      = tid >> 6;   // 0..3 batch sub-group
    const int n       = node0 + n_local;
    const int bbase   = b0 + bq * 4;

    // ---- t-fill: 16x ds_read_b128 (conflict-free via swizzle), then ----
    // ---- level-0 (base,diff) pairs, reused across all 4 batches      ----
    float tb[32], td[32];
    #pragma unroll
    for (int k = 0; k < 16; ++k) {
        const float4 v = *(const float4*)&lt[n_local * 64 + ((k ^ (n_local & 15)) << 2)];
        tb[2*k]   = v.x;  td[2*k]   = v.y - v.x;
        tb[2*k+1] = v.z;  td[2*k+1] = v.w - v.z;
    }

    // ---- Depth-2 rolling x prefetch: 2 batches (6 dwordx2) in flight ----
    float2 p[2][3];
    #pragma unroll
    for (int b = 0; b < 2; ++b) {
        const float2* xp = (const float2*)(x + ((long)(bbase + b) * 8192 + n) * 6);
        p[b][0] = xp[0]; p[b][1] = xp[1]; p[b][2] = xp[2];
    }

    #pragma unroll
    for (int bl = 0; bl < 4; ++bl) {
        const float2 c0 = p[bl & 1][0];
        const float2 c1 = p[bl & 1][1];
        const float2 c2 = p[bl & 1][2];

        if (bl < 2) {  // refill the slot just freed with batch bl+2
            const float2* xn = (const float2*)(x + ((long)(bbase + bl + 2) * 8192 + n) * 6);
            p[bl & 1][0] = xn[0]; p[bl & 1][1] = xn[1]; p[bl & 1][2] = xn[2];
        }

        const float x0 = fminf(fmaxf(c0.x, 0.f), 1.f);
        const float x1 = fminf(fmaxf(c0.y, 0.f), 1.f);
        const float x2 = fminf(fmaxf(c1.x, 0.f), 1.f);
        const float x3 = fminf(fmaxf(c1.y, 0.f), 1.f);
        const float x4 = fminf(fmaxf(c2.x, 0.f), 1.f);
        const float x5 = fminf(fmaxf(c2.y, 0.f), 1.f);

        float a[32];
        #pragma unroll
        for (int j = 0; j < 32; ++j) a[j] = fmaf(x0, td[j], tb[j]);
        #pragma unroll
        for (int j = 0; j < 16; ++j) a[j] = fmaf(x1, a[2*j+1] - a[2*j], a[2*j]);
        #pragma unroll
        for (int j = 0; j < 8;  ++j) a[j] = fmaf(x2, a[2*j+1] - a[2*j], a[2*j]);
        #pragma unroll
        for (int j = 0; j < 4;  ++j) a[j] = fmaf(x3, a[2*j+1] - a[2*j], a[2*j]);
        #pragma unroll
        for (int j = 0; j < 2;  ++j) a[j] = fmaf(x4, a[2*j+1] - a[2*j], a[2*j]);
        const float r = fmaf(x5, a[1] - a[0], a[0]);

        out[(long)(bbase + bl) * 8192 + n] = r;   // coalesced
    }
}

extern "C" void kernel_launch(void* const* d_in, const int* in_sizes, int n_in,
                              void* d_out, int out_size, void* d_ws, size_t ws_size,
                              hipStream_t stream) {
    const float* x      = (const float*)d_in[0];   // 128*8192*6 f32
    const float* tables = (const float*)d_in[1];   // 8192*64 f32
    float* out          = (float*)d_out;           // 128*8192 f32

    dim3 grid(1024);   // 128 node tiles x 8 batch groups = 4 blocks/CU
    dim3 block(THREADS);
    hipLaunchKernelGGL(lut_fold_kernel, grid, block, 0, stream, x, tables, out);
}